// Round 8
// baseline (79.015 us; speedup 1.0000x reference)
//
#include <hip/hip_runtime.h>

typedef float f4v __attribute__((ext_vector_type(4)));
typedef float f32x4 __attribute__((ext_vector_type(4)));
typedef __bf16 bf16x8 __attribute__((ext_vector_type(8)));
typedef __bf16 bf16x4 __attribute__((ext_vector_type(4)));
typedef unsigned short ushort8 __attribute__((ext_vector_type(8)));

static constexpr int KDIM = 2048;

// workspace layout (bytes)
static constexpr size_t OFF_XN      = 0;                                     // ushort [3][256][2048]  (3 MB)
static constexpr size_t OFF_PART    = (size_t)3 * 256 * 2048 * 2;            // float  [768][256][4]   (3 MB)
static constexpr size_t OFF_DOTT    = OFF_PART + (size_t)768 * 256 * 16;     // float  [768]
static constexpr size_t OFF_ROWLOSS = OFF_DOTT + 768 * 4;                    // float  [768]

__device__ __forceinline__ unsigned short f2bf(float x) {
  union { float f; unsigned u; } c; c.f = x;
  unsigned r = c.u + 0x7fffu + ((c.u >> 16) & 1u);   // RNE
  return (unsigned short)(r >> 16);
}

__device__ __forceinline__ void gload_lds16(const void* g, void* l) {
  __builtin_amdgcn_global_load_lds((const __attribute__((address_space(1))) void*)g,
                                   (__attribute__((address_space(3))) void*)l,
                                   16, 0, 0);
}

// two f32x4 -> bf16x8 (compiler emits v_cvt_pk_bf16_f32)
__device__ __forceinline__ bf16x8 cvt8(f4v lo, f4v hi) {
  bf16x8 r;
  r[0] = (__bf16)lo[0]; r[1] = (__bf16)lo[1]; r[2] = (__bf16)lo[2]; r[3] = (__bf16)lo[3];
  r[4] = (__bf16)hi[0]; r[5] = (__bf16)hi[1]; r[6] = (__bf16)hi[2]; r[7] = (__bf16)hi[3];
  return r;
}

// ---------------- kernel 1: row-normalize inputs -> bf16 ----------------
__global__ __launch_bounds__(256) void k_normalize(
    const float* __restrict__ x0, const float* __restrict__ x1, const float* __restrict__ x2,
    unsigned short* __restrict__ xn)
{
  int bid = blockIdx.x;            // 0..767 : branch*256 + row
  int branch = bid >> 8;
  int row = bid & 255;
  const float* src = (branch == 0 ? x0 : (branch == 1 ? x1 : x2)) + (size_t)row * KDIM;
  int tid = threadIdx.x;
  f4v a = *(const f4v*)(src + tid * 8);
  f4v b = *(const f4v*)(src + tid * 8 + 4);
  float s = a[0]*a[0] + a[1]*a[1] + a[2]*a[2] + a[3]*a[3]
          + b[0]*b[0] + b[1]*b[1] + b[2]*b[2] + b[3]*b[3];
  #pragma unroll
  for (int m = 1; m < 64; m <<= 1) s += __shfl_xor(s, m);
  __shared__ float ls[4];
  if ((tid & 63) == 0) ls[tid >> 6] = s;
  __syncthreads();
  float total = ls[0] + ls[1] + ls[2] + ls[3];
  float inv = 1.0f / fmaxf(sqrtf(total), 1e-12f);
  ushort8 u;
  #pragma unroll
  for (int e = 0; e < 4; ++e) u[e]     = f2bf(a[e] * inv);
  #pragma unroll
  for (int e = 0; e < 4; ++e) u[4 + e] = f2bf(b[e] * inv);
  *(ushort8*)(xn + (size_t)bid * KDIM + tid * 8) = u;
}

// ---------------- kernel 2: fused GEMM + per-tile reductions ----------------
// BM=64, BN=64, BK=64. Grid = 3 x 4 mtiles x 128 ntiles = 1536 = 6 blocks/CU
// (24 waves/CU): occupancy-driven latency hiding (m114), m97 2-phase loop.
// 4 waves (2M x 2N), each computing 32x32.
// A (bf16 xn, 8 KB) and B (raw f32 features, 16 KB) both staged with
// global_load_lds (pre-swizzled source, linear LDS dest). Single-buffered,
// 24 KB LDS. B converted f32->bf16 at fragment read (cvt_pk).
__global__ __launch_bounds__(256, 6) void k_gemm_fused(
    const unsigned short* __restrict__ xn,
    const float* __restrict__ f0, const float* __restrict__ f1, const float* __restrict__ f2,
    const int* __restrict__ targets,
    float* __restrict__ part, float* __restrict__ dotT)
{
  // A: [0, 8192) = 64 rows x 8 chunks x 16B (chunk ^ (row&7))
  // B: [8192, 24576) = 64 cols x 16 chunks x 16B (chunk ^ (col&15))
  __shared__ char lds[24576];

  int bid = blockIdx.x;
  int swz = (bid & 7) * 192 + (bid >> 3);  // XCD-aware, 1536 % 8 == 0 -> bijective
  int branch = swz >> 9;                   // 512 blocks per branch
  int rem = swz & 511;
  int ntile = rem >> 2;                    // 128 n-tiles of 64 cols
  int mtile = rem & 3;                     // 4 m-tiles of 64 rows, adjacent -> share B in L2

  const unsigned short* A = xn + ((size_t)branch * 256 + (size_t)mtile * 64) * KDIM;
  const float* F = (branch == 0 ? f0 : (branch == 1 ? f1 : f2)) + (size_t)ntile * 64 * KDIM;

  int tid = threadIdx.x;
  int wave = tid >> 6;
  int lane = tid & 63;
  int rcol0 = lane & 15;
  int klane = lane >> 4;
  int wr = wave >> 1;    // M half
  int wc = wave & 1;     // N half

  // ---- A staging: 2 x gload_lds(16B)/thread. c = g*256+tid: row=c>>3, chunk=(c&7)^(row&7)
  const unsigned short* aSrc = A + (size_t)(tid >> 3) * KDIM
                             + (((tid & 7) ^ ((tid >> 3) & 7)) << 3);
  // ---- B staging: 4 x gload_lds(16B)/thread. c = g*256+tid: col=c>>4, chunk=(c&15)^(col&15)
  const float* bSrc = F + (size_t)(tid >> 4) * KDIM
                    + (((tid & 15) ^ ((tid >> 4) & 15)) << 2);
  char* aDst = lds + wave * 1024;          // + g*4096
  char* bDst = lds + 8192 + wave * 1024;   // + g*4096

#define STAGE(kt) do { \
    gload_lds16(aSrc + (kt) * 64, aDst); \
    gload_lds16(aSrc + (size_t)32 * KDIM + (kt) * 64, aDst + 4096); \
    _Pragma("unroll") for (int g = 0; g < 4; ++g) \
      gload_lds16(bSrc + (size_t)g * 16 * KDIM + (kt) * 64, bDst + g * 4096); \
  } while (0)

  f32x4 acc[2][2];
  #pragma unroll
  for (int i = 0; i < 2; ++i)
    #pragma unroll
    for (int j = 0; j < 2; ++j)
      #pragma unroll
      for (int q = 0; q < 4; ++q) acc[i][j][q] = 0.0f;

  int sa = rcol0 & 7;
  // A read: row = wr*32 + i*16 + rcol0 -> byte row*128 + ((ks*4+klane)^sa)*16
  const char* aRd = lds + (wr * 32 + rcol0) * 128;
  // B read: col = wc*32 + j*16 + rcol0 -> byte 8192 + col*256 + ((x^rcol0))*16, x=ks*8+klane*2
  const char* bRd = lds + 8192 + (wc * 32 + rcol0) * 256;

#define COMPUTE() do { \
    _Pragma("unroll") for (int ks = 0; ks < 2; ++ks) { \
      int chA = (((ks * 4 + klane) ^ sa) << 4); \
      int x = ks * 8 + klane * 2; \
      int chB0 = ((x ^ rcol0) << 4); \
      int chB1 = (((x + 1) ^ rcol0) << 4); \
      f4v lo0 = *(const f4v*)(bRd + chB0); \
      f4v hi0 = *(const f4v*)(bRd + chB1); \
      f4v lo1 = *(const f4v*)(bRd + 4096 + chB0); \
      f4v hi1 = *(const f4v*)(bRd + 4096 + chB1); \
      bf16x8 b0 = cvt8(lo0, hi0); \
      bf16x8 b1 = cvt8(lo1, hi1); \
      bf16x8 a0 = *(const bf16x8*)(aRd + chA); \
      bf16x8 a1 = *(const bf16x8*)(aRd + 2048 + chA); \
      acc[0][0] = __builtin_amdgcn_mfma_f32_16x16x32_bf16(a0, b0, acc[0][0], 0, 0, 0); \
      acc[0][1] = __builtin_amdgcn_mfma_f32_16x16x32_bf16(a0, b1, acc[0][1], 0, 0, 0); \
      acc[1][0] = __builtin_amdgcn_mfma_f32_16x16x32_bf16(a1, b0, acc[1][0], 0, 0, 0); \
      acc[1][1] = __builtin_amdgcn_mfma_f32_16x16x32_bf16(a1, b1, acc[1][1], 0, 0, 0); \
    } \
  } while (0)

  // m97 2-phase loop: {stage; barrier; compute; barrier}
  STAGE(0);
  __syncthreads();
  for (int kt = 0; kt < 31; ++kt) {
    COMPUTE();
    __syncthreads();
    STAGE(kt + 1);
    __syncthreads();
  }
  COMPUTE();

#undef STAGE
#undef COMPUTE

  // fused epilogue: per-row partials over this wave's 32-col span.
  // p1 = sum exp(20d-20), Z1 = sum exp(D-2), Z2 = sum exp(2(D-2)), Z3 = sum exp(3(D-2))
  // D = sqrt(max(2-2d,0)).  C/D layout: col = lane&15, row = klane*4 + q.
  int tbase = branch * 256;
  int mbase = mtile * 64;
  #pragma unroll
  for (int i = 0; i < 2; ++i) {
    #pragma unroll
    for (int q = 0; q < 4; ++q) {
      int row = mbase + wr * 32 + i * 16 + (klane << 2) + q;   // row in [0,256)
      int tgt = targets[row];
      float s1 = 0.f, s2 = 0.f, s3 = 0.f, s4 = 0.f;
      #pragma unroll
      for (int j = 0; j < 2; ++j) {
        float d = acc[i][j][q];
        float e1 = __expf(fmaf(20.0f, d, -20.0f));
        float Dv = sqrtf(fmaxf(2.0f - 2.0f * d, 0.0f));
        float e2 = __expf(Dv - 2.0f);
        s1 += e1; s2 += e2;
        float t2 = e2 * e2;
        s3 += t2; s4 += t2 * e2;
        int col = ntile * 64 + wc * 32 + j * 16 + rcol0;
        if (col == tgt) dotT[tbase + row] = d;   // exactly one writer per row globally
      }
      #pragma unroll
      for (int m = 1; m < 16; m <<= 1) {         // reduce across 16 lanes sharing this row
        s1 += __shfl_xor(s1, m);
        s2 += __shfl_xor(s2, m);
        s3 += __shfl_xor(s3, m);
        s4 += __shfl_xor(s4, m);
      }
      if (rcol0 == 0) {
        f32x4 p; p[0] = s1; p[1] = s2; p[2] = s3; p[3] = s4;
        *(f32x4*)(part + ((size_t)(tbase + row) * 256 + ntile * 2 + wc) * 4) = p;
      }
    }
  }
}

// ---------------- kernel 3: combine 256 tile-partials per row -> row loss ----------------
__global__ __launch_bounds__(256) void k_combine(
    const float* __restrict__ part, const float* __restrict__ dotT, float* __restrict__ rowloss)
{
  int row = blockIdx.x;    // 0..767
  int tid = threadIdx.x;   // 256
  f4v p = *(const f4v*)(part + ((size_t)row * 256 + tid) * 4);
  float a0 = p[0], a1 = p[1], a2 = p[2], a3 = p[3];
  #pragma unroll
  for (int m = 1; m < 64; m <<= 1) {
    a0 += __shfl_xor(a0, m); a1 += __shfl_xor(a1, m);
    a2 += __shfl_xor(a2, m); a3 += __shfl_xor(a3, m);
  }
  __shared__ float ls[4][4];
  if ((tid & 63) == 0) {
    int w = tid >> 6;
    ls[0][w] = a0; ls[1][w] = a1; ls[2][w] = a2; ls[3][w] = a3;
  }
  __syncthreads();
  if (tid == 0) {
    float p1 = ls[0][0] + ls[0][1] + ls[0][2] + ls[0][3];
    float Z1 = ls[1][0] + ls[1][1] + ls[1][2] + ls[1][3];
    float Z2 = ls[2][0] + ls[2][1] + ls[2][2] + ls[2][3];
    float Z3 = ls[3][0] + ls[3][1] + ls[3][2] + ls[3][3];
    float dt = dotT[row];
    // CE1 = logsumexp(20*dot) - 20*dot_t   (fixed shift 20 is exact: 20d-20 <= 0)
    float CE1 = 20.0f + logf(p1) - 20.0f * dt;
    // CE2 = log(sum_n exp(S_n)) - S_t ;  sum_n exp(S_n) = N + 1 + Z2/(2 Z1^2) + Z3/(6 Z1^3)
    float Dt = sqrtf(fmaxf(2.0f - 2.0f * dt, 0.0f));
    float St = __expf(Dt - 2.0f) / Z1;
    float sES = 8193.0f + Z2 / (2.0f * Z1 * Z1) + Z3 / (6.0f * Z1 * Z1 * Z1);
    float CE2 = logf(sES) - St;
    rowloss[row] = (CE1 + CE2) * (0.5f / 256.0f);
  }
}

// ---------------- kernel 4: final sum ----------------
__global__ __launch_bounds__(256) void k_final(const float* __restrict__ rowloss, float* __restrict__ out)
{
  int tid = threadIdx.x;
  float v = rowloss[tid] + rowloss[tid + 256] + rowloss[tid + 512];
  #pragma unroll
  for (int m = 1; m < 64; m <<= 1) v += __shfl_xor(v, m);
  __shared__ float ls[4];
  if ((tid & 63) == 0) ls[tid >> 6] = v;
  __syncthreads();
  if (tid == 0) out[0] = ls[0] + ls[1] + ls[2] + ls[3];
}

extern "C" void kernel_launch(void* const* d_in, const int* in_sizes, int n_in,
                              void* d_out, int out_size, void* d_ws, size_t ws_size,
                              hipStream_t stream) {
  const float* in0 = (const float*)d_in[0];
  const float* in1 = (const float*)d_in[1];
  const float* in2 = (const float*)d_in[2];
  const int* targets = (const int*)d_in[3];
  // d_in[4] = epoch (unused by the loss)
  const float* f0 = (const float*)d_in[5];
  const float* f1 = (const float*)d_in[6];
  const float* f2 = (const float*)d_in[7];

  char* ws = (char*)d_ws;
  unsigned short* xn = (unsigned short*)(ws + OFF_XN);
  float* part    = (float*)(ws + OFF_PART);
  float* dotT    = (float*)(ws + OFF_DOTT);
  float* rowloss = (float*)(ws + OFF_ROWLOSS);
  float* out = (float*)d_out;

  k_normalize<<<768, 256, 0, stream>>>(in0, in1, in2, xn);
  k_gemm_fused<<<1536, 256, 0, stream>>>(xn, f0, f1, f2, targets, part, dotT);
  k_combine<<<768, 256, 0, stream>>>(part, dotT, rowloss);
  k_final<<<1, 256, 0, stream>>>(rowloss, out);
}

// Round 9
// 66.122 us; speedup vs baseline: 1.1950x; 1.1950x over previous
//
#include <hip/hip_runtime.h>

typedef float f4v __attribute__((ext_vector_type(4)));
typedef float f32x4 __attribute__((ext_vector_type(4)));
typedef __bf16 bf16x8 __attribute__((ext_vector_type(8)));
typedef unsigned short ushort8 __attribute__((ext_vector_type(8)));

static constexpr int KDIM = 2048;

// workspace layout (bytes)
static constexpr size_t OFF_XN      = 0;                                     // ushort [3][256][2048]  (3 MB)
static constexpr size_t OFF_PART    = (size_t)3 * 256 * 2048 * 2;            // float  [768][128][4]   (1.5 MB)
static constexpr size_t OFF_DOTT    = OFF_PART + (size_t)768 * 128 * 16;     // float  [768]
static constexpr size_t OFF_ROWLOSS = OFF_DOTT + 768 * 4;                    // float  [768]

__device__ __forceinline__ unsigned short f2bf(float x) {
  union { float f; unsigned u; } c; c.f = x;
  unsigned r = c.u + 0x7fffu + ((c.u >> 16) & 1u);   // RNE
  return (unsigned short)(r >> 16);
}

__device__ __forceinline__ void gload_lds16(const void* g, void* l) {
  __builtin_amdgcn_global_load_lds((const __attribute__((address_space(1))) void*)g,
                                   (__attribute__((address_space(3))) void*)l,
                                   16, 0, 0);
}

// two f32x4 -> bf16x8 (compiler emits v_cvt_pk_bf16_f32)
__device__ __forceinline__ bf16x8 cvt8(f4v lo, f4v hi) {
  bf16x8 r;
  r[0] = (__bf16)lo[0]; r[1] = (__bf16)lo[1]; r[2] = (__bf16)lo[2]; r[3] = (__bf16)lo[3];
  r[4] = (__bf16)hi[0]; r[5] = (__bf16)hi[1]; r[6] = (__bf16)hi[2]; r[7] = (__bf16)hi[3];
  return r;
}

// ---------------- kernel 1: row-normalize inputs -> bf16 ----------------
__global__ __launch_bounds__(256) void k_normalize(
    const float* __restrict__ x0, const float* __restrict__ x1, const float* __restrict__ x2,
    unsigned short* __restrict__ xn)
{
  int bid = blockIdx.x;            // 0..767 : branch*256 + row
  int branch = bid >> 8;
  int row = bid & 255;
  const float* src = (branch == 0 ? x0 : (branch == 1 ? x1 : x2)) + (size_t)row * KDIM;
  int tid = threadIdx.x;
  f4v a = *(const f4v*)(src + tid * 8);
  f4v b = *(const f4v*)(src + tid * 8 + 4);
  float s = a[0]*a[0] + a[1]*a[1] + a[2]*a[2] + a[3]*a[3]
          + b[0]*b[0] + b[1]*b[1] + b[2]*b[2] + b[3]*b[3];
  #pragma unroll
  for (int m = 1; m < 64; m <<= 1) s += __shfl_xor(s, m);
  __shared__ float ls[4];
  if ((tid & 63) == 0) ls[tid >> 6] = s;
  __syncthreads();
  float total = ls[0] + ls[1] + ls[2] + ls[3];
  float inv = 1.0f / fmaxf(sqrtf(total), 1e-12f);
  ushort8 u;
  #pragma unroll
  for (int e = 0; e < 4; ++e) u[e]     = f2bf(a[e] * inv);
  #pragma unroll
  for (int e = 0; e < 4; ++e) u[4 + e] = f2bf(b[e] * inv);
  *(ushort8*)(xn + (size_t)bid * KDIM + tid * 8) = u;
}

// ---------------- kernel 2: fused GEMM + per-tile reductions ----------------
// Traffic-minimal geometry: BM=256 (whole batch), BN=128, BK=64.
// Staged traffic = 192 MB (A re-staged 64x/branch) + 192 MB (B once) = 384 MB
// (3x less than round 8) -- the measured ~8-10 TB/s fill ceiling is the limit.
// Grid = 3 x 64 = 192 blocks, 512 threads (8 waves, 4M x 2N, wave-tile 64x64).
// Both operands via global_load_lds (pre-swizzled source, linear LDS dest),
// double-buffered, m97 2-phase loop (stage issued before compute each tile).
__global__ __launch_bounds__(512, 1) void k_gemm_fused(
    const unsigned short* __restrict__ xn,
    const float* __restrict__ f0, const float* __restrict__ f1, const float* __restrict__ f2,
    const int* __restrict__ targets,
    float* __restrict__ part, float* __restrict__ dotT)
{
  // per buffer (64 KB): A [0,32768) = 256 rows x 8 chunks16B (chunk ^ row&7)
  //                     B [32768,65536) = 128 cols x 16 chunks16B (chunk ^ col&15), raw f32
  __shared__ char lds[2 * 65536];

  int bid = blockIdx.x;
  int swz = (bid & 7) * 24 + (bid >> 3);   // XCD-aware, 192 % 8 == 0 -> bijective
  int branch = swz >> 6;                   // 64 blocks per branch
  int ntile = swz & 63;                    // 64 n-tiles of 128 cols

  const unsigned short* A = xn + (size_t)branch * 256 * KDIM;
  const float* F = (branch == 0 ? f0 : (branch == 1 ? f1 : f2)) + (size_t)ntile * 128 * KDIM;

  int tid = threadIdx.x;                   // 0..511
  int wave = tid >> 6;                     // 0..7
  int lane = tid & 63;
  int rcol0 = lane & 15;
  int klane = lane >> 4;
  int wr = wave >> 1;    // M quadrant (0..3), 64 rows each
  int wc = wave & 1;     // N half (0..1), 64 cols each

  // ---- A staging: 4 x gload_lds(16B)/thread. c = g*512+tid: row = c>>3 = g*64+(tid>>3),
  // phys chunk = c&7, logical = (c&7)^(row&7); row&7 independent of g.
  const unsigned short* aSrc = A + (size_t)(tid >> 3) * KDIM
                             + (((tid & 7) ^ ((tid >> 3) & 7)) << 3);
  // ---- B staging: 4 x gload_lds(16B)/thread. c = g*512+tid: col = g*32+(tid>>4),
  // chunk = (c&15)^(col&15); col&15 independent of g.
  const float* bSrc = F + (size_t)(tid >> 4) * KDIM
                    + (((tid & 15) ^ ((tid >> 4) & 15)) << 2);
  char* aDst = lds + wave * 1024;          // + buf*65536 + g*8192 (lane*16 implicit)
  char* bDst = lds + 32768 + wave * 1024;  // + buf*65536 + g*8192

#define STAGE(kt, buf) do { \
    _Pragma("unroll") for (int g = 0; g < 4; ++g) \
      gload_lds16(aSrc + (size_t)g * 64 * KDIM + (kt) * 64, \
                  aDst + (buf) * 65536 + g * 8192); \
    _Pragma("unroll") for (int g = 0; g < 4; ++g) \
      gload_lds16(bSrc + (size_t)g * 32 * KDIM + (kt) * 64, \
                  bDst + (buf) * 65536 + g * 8192); \
  } while (0)

  f32x4 acc[4][4];
  #pragma unroll
  for (int i = 0; i < 4; ++i)
    #pragma unroll
    for (int j = 0; j < 4; ++j)
      #pragma unroll
      for (int q = 0; q < 4; ++q) acc[i][j][q] = 0.0f;

  int sa = rcol0 & 7;
  // A read: row = wr*64 + i*16 + rcol0; byte = row*128 + ((ks*4+klane)^sa)*16
  const char* aRd = lds + (wr * 64 + rcol0) * 128;
  // B read: col = wc*64 + j*16 + rcol0 (col&15 = rcol0); byte = 32768 + col*256 + ((x^rcol0))*16
  const char* bRd = lds + 32768 + (wc * 64 + rcol0) * 256;

#define COMPUTE(buf) do { \
    const char* ra = aRd + (buf) * 65536; \
    const char* rb = bRd + (buf) * 65536; \
    _Pragma("unroll") for (int ks = 0; ks < 2; ++ks) { \
      int chA = (((ks * 4 + klane) ^ sa) << 4); \
      int x = ks * 8 + klane * 2; \
      int chB0 = ((x ^ rcol0) << 4); \
      int chB1 = (((x + 1) ^ rcol0) << 4); \
      bf16x8 a0 = *(const bf16x8*)(ra + chA); \
      bf16x8 a1 = *(const bf16x8*)(ra + 2048 + chA); \
      bf16x8 a2 = *(const bf16x8*)(ra + 4096 + chA); \
      bf16x8 a3 = *(const bf16x8*)(ra + 6144 + chA); \
      _Pragma("unroll") for (int j = 0; j < 4; ++j) { \
        f4v lo = *(const f4v*)(rb + j * 4096 + chB0); \
        f4v hi = *(const f4v*)(rb + j * 4096 + chB1); \
        bf16x8 bj = cvt8(lo, hi); \
        acc[0][j] = __builtin_amdgcn_mfma_f32_16x16x32_bf16(a0, bj, acc[0][j], 0, 0, 0); \
        acc[1][j] = __builtin_amdgcn_mfma_f32_16x16x32_bf16(a1, bj, acc[1][j], 0, 0, 0); \
        acc[2][j] = __builtin_amdgcn_mfma_f32_16x16x32_bf16(a2, bj, acc[2][j], 0, 0, 0); \
        acc[3][j] = __builtin_amdgcn_mfma_f32_16x16x32_bf16(a3, bj, acc[3][j], 0, 0, 0); \
      } \
    } \
  } while (0)

  // m97 2-phase loop, stage issued before compute each tile
  STAGE(0, 0);
  __syncthreads();
  for (int kt = 0; kt < 31; ++kt) {
    int cur = kt & 1;
    STAGE(kt + 1, cur ^ 1);    // issue next tile's loads first (hide under compute)
    COMPUTE(cur);
    __syncthreads();           // drains vmcnt; next buffer ready
  }
  COMPUTE(1);

#undef STAGE
#undef COMPUTE

  // fused epilogue: per-row partials over this wave's 64-col span.
  // p1 = sum exp(20d-20), Z1 = sum exp(D-2), Z2 = sum exp(2(D-2)), Z3 = sum exp(3(D-2))
  // D = sqrt(max(2-2d,0)).  C/D layout: col = lane&15, row = klane*4 + q.
  int tbase = branch * 256;
  #pragma unroll
  for (int i = 0; i < 4; ++i) {
    #pragma unroll
    for (int q = 0; q < 4; ++q) {
      int row = wr * 64 + i * 16 + (klane << 2) + q;   // row in [0,256)
      int tgt = targets[row];
      float s1 = 0.f, s2 = 0.f, s3 = 0.f, s4 = 0.f;
      #pragma unroll
      for (int j = 0; j < 4; ++j) {
        float d = acc[i][j][q];
        float e1 = __expf(fmaf(20.0f, d, -20.0f));
        float Dv = sqrtf(fmaxf(2.0f - 2.0f * d, 0.0f));
        float e2 = __expf(Dv - 2.0f);
        s1 += e1; s2 += e2;
        float t2 = e2 * e2;
        s3 += t2; s4 += t2 * e2;
        int col = ntile * 128 + wc * 64 + j * 16 + rcol0;
        if (col == tgt) dotT[tbase + row] = d;   // exactly one writer per row globally
      }
      #pragma unroll
      for (int m = 1; m < 16; m <<= 1) {         // reduce across 16 lanes sharing this row
        s1 += __shfl_xor(s1, m);
        s2 += __shfl_xor(s2, m);
        s3 += __shfl_xor(s3, m);
        s4 += __shfl_xor(s4, m);
      }
      if (rcol0 == 0) {
        f32x4 p; p[0] = s1; p[1] = s2; p[2] = s3; p[3] = s4;
        *(f32x4*)(part + ((size_t)(tbase + row) * 128 + ntile * 2 + wc) * 4) = p;
      }
    }
  }
}

// ---------------- kernel 3: combine 128 tile-partials per row -> row loss ----------------
__global__ __launch_bounds__(128) void k_combine(
    const float* __restrict__ part, const float* __restrict__ dotT, float* __restrict__ rowloss)
{
  int row = blockIdx.x;    // 0..767
  int tid = threadIdx.x;   // 128
  f4v p = *(const f4v*)(part + ((size_t)row * 128 + tid) * 4);
  float a0 = p[0], a1 = p[1], a2 = p[2], a3 = p[3];
  #pragma unroll
  for (int m = 1; m < 64; m <<= 1) {
    a0 += __shfl_xor(a0, m); a1 += __shfl_xor(a1, m);
    a2 += __shfl_xor(a2, m); a3 += __shfl_xor(a3, m);
  }
  __shared__ float ls[8];
  if ((tid & 63) == 0) {
    int w = tid >> 6;
    ls[w] = a0; ls[2 + w] = a1; ls[4 + w] = a2; ls[6 + w] = a3;
  }
  __syncthreads();
  if (tid == 0) {
    float p1 = ls[0] + ls[1];
    float Z1 = ls[2] + ls[3];
    float Z2 = ls[4] + ls[5];
    float Z3 = ls[6] + ls[7];
    float dt = dotT[row];
    // CE1 = logsumexp(20*dot) - 20*dot_t   (fixed shift 20 is exact: 20d-20 <= 0)
    float CE1 = 20.0f + logf(p1) - 20.0f * dt;
    // CE2 = log(sum_n exp(S_n)) - S_t ;  sum_n exp(S_n) = N + 1 + Z2/(2 Z1^2) + Z3/(6 Z1^3)
    float Dt = sqrtf(fmaxf(2.0f - 2.0f * dt, 0.0f));
    float St = __expf(Dt - 2.0f) / Z1;
    float sES = 8193.0f + Z2 / (2.0f * Z1 * Z1) + Z3 / (6.0f * Z1 * Z1 * Z1);
    float CE2 = logf(sES) - St;
    rowloss[row] = (CE1 + CE2) * (0.5f / 256.0f);
  }
}

// ---------------- kernel 4: final sum ----------------
__global__ __launch_bounds__(256) void k_final(const float* __restrict__ rowloss, float* __restrict__ out)
{
  int tid = threadIdx.x;
  float v = rowloss[tid] + rowloss[tid + 256] + rowloss[tid + 512];
  #pragma unroll
  for (int m = 1; m < 64; m <<= 1) v += __shfl_xor(v, m);
  __shared__ float ls[4];
  if ((tid & 63) == 0) ls[tid >> 6] = v;
  __syncthreads();
  if (tid == 0) out[0] = ls[0] + ls[1] + ls[2] + ls[3];
}

extern "C" void kernel_launch(void* const* d_in, const int* in_sizes, int n_in,
                              void* d_out, int out_size, void* d_ws, size_t ws_size,
                              hipStream_t stream) {
  const float* in0 = (const float*)d_in[0];
  const float* in1 = (const float*)d_in[1];
  const float* in2 = (const float*)d_in[2];
  const int* targets = (const int*)d_in[3];
  // d_in[4] = epoch (unused by the loss)
  const float* f0 = (const float*)d_in[5];
  const float* f1 = (const float*)d_in[6];
  const float* f2 = (const float*)d_in[7];

  char* ws = (char*)d_ws;
  unsigned short* xn = (unsigned short*)(ws + OFF_XN);
  float* part    = (float*)(ws + OFF_PART);
  float* dotT    = (float*)(ws + OFF_DOTT);
  float* rowloss = (float*)(ws + OFF_ROWLOSS);
  float* out = (float*)d_out;

  k_normalize<<<768, 256, 0, stream>>>(in0, in1, in2, xn);
  k_gemm_fused<<<192, 512, 0, stream>>>(xn, f0, f1, f2, targets, part, dotT);
  k_combine<<<768, 128, 0, stream>>>(part, dotT, rowloss);
  k_final<<<1, 256, 0, stream>>>(rowloss, out);
}